// Round 17
// baseline (75.278 us; speedup 1.0000x reference)
//
#include <hip/hip_runtime.h>
#include <hip/hip_bf16.h>
#include <hip/hip_cooperative_groups.h>

namespace cg = cooperative_groups;

// Problem dims (fixed)
#define BB   8
#define LL   32
#define NINV 64
#define NOUTV 16
#define DINV 128
#define EE   64
#define DCV  512

#define EPSF 1e-8f
#define LBDF 1e-3f
// 32 * ln(2*pi)
#define SUM_LN2PI 58.8120661250990508f

// f16 MFMA scaling: A(u) x 2^12, B(sc*Wv) x 2^10, descale 2^-22
#define SA_F 4096.0f
#define SB_F 1024.0f
#define DESCALE (1.0f / 4194304.0f)

typedef float f32x4v __attribute__((ext_vector_type(4)));
typedef _Float16 f16x8 __attribute__((ext_vector_type(8)));
typedef __fp16 fp16x2 __attribute__((ext_vector_type(2)));

union pk16 { fp16x2 h; unsigned int u; };

static __device__ __forceinline__ unsigned int cvt_pk_bf16(float lo, float hi) {
    unsigned int r;
    asm("v_cvt_pk_bf16_f32 %0, %1, %2" : "=v"(r) : "v"(lo), "v"(hi));
    return r;
}

// ---------------------------------------------------------------------------
// ONE cooperative kernel, grid = 256 blocks x 1024 threads (1 block/CU,
// co-residency forced by 140 KB LDS).
// Phase 1 (block bl): 4 subgroups x 256 thr compute priors+u16 for
//   no = bl*4+g (R14 code); then prep-c for THIS bl -> scwv/vbar in LDS
//   (never leave the block); blocks 0..7 compute actn -> global.
// grid.sync()  (u16 slices + actn cross block boundaries; scwv does not)
// Phase 2: em (R16 structure) with two changes:
//   (a) MFMA operands swapped: mfma(scwv_frag, u_frag) -> acc regs walk e
//       (A/B frag lane layouts are symmetric, loads unchanged) -> dv store
//       becomes ONE ds_write_b64 per (rt,ct) instead of 4 ds_write_b16.
//   (b) scwv B-frags read from swizzled LDS (conflict-free b128).
// Rationale: R12->R14 showed ~8us/launch-node saved; two serialized graph
// nodes + full drain explain the gap between 43us measured and ~22us of
// modeled work. This removes the last extra node + the scwv round-trip.
// ---------------------------------------------------------------------------
__global__ __launch_bounds__(1024) void fused_all_kernel(
    const float* __restrict__ inu, const float* __restrict__ rw,
    const float* __restrict__ Wu, const float* __restrict__ bu,
    const float* __restrict__ ctx, const float* __restrict__ Wc, const float* __restrict__ bc,
    const float* __restrict__ Wv, const float* __restrict__ bv,
    const float* __restrict__ Wa, const float* __restrict__ ba,
    const unsigned char* __restrict__ mask_all,
    const float* __restrict__ beta_u, const float* __restrict__ beta_a,
    _Float16* __restrict__ u16, float* __restrict__ a_ws,
    float* __restrict__ out_mu, float* __restrict__ out_r)
{
    const int bl = blockIdx.x;           // 0..255  (= b*32 + l)
    const int b = bl >> 5;
    const int tid = threadIdx.x;
    const int n = tid >> 4;
    const int o = tid & 15;
    const int wid = tid >> 6;            // wave 0..15
    const int lane = tid & 63;
    const int l15 = lane & 15;
    const int lk = (lane >> 4) * 8;

    __shared__ __align__(16) unsigned int dv_sh[NINV * NOUTV * (EE / 2)]; // 128 KB
    __shared__ __align__(16) _Float16 scwv_sh[EE * EE];                   // 8 KB, swizzled
    __shared__ __align__(16) float dmu_sh[NOUTV][68];
    __shared__ __align__(16) float q_sh[NOUTV][68];
    __shared__ __align__(16) float ar_t[NOUTV][68];
    __shared__ float actn_sh[NINV];
    __shared__ float vbar_sh[EE];
    __shared__ float sumhl_sh[NOUTV];
    __shared__ float logact_sh[NOUTV];

    char* dvb = (char*)dv_sh;
    float* ph1 = (float*)dv_sh;          // phase-1 scratch aliases dv region

    // ================= Phase 1 =================
    {
        const int g = tid >> 8;          // subgroup 0..3
        const int stid = tid & 255;
        const int no = bl * 4 + g;       // (n,o) tile handled by this subgroup
        const int n_p = no >> 4;
        float* inu_sh = ph1 + g * 1600;          // 1024 floats
        float* pri_sh = ph1 + g * 1600 + 1024;   // 8 x 68

        {   // stage inu[:, n_p, :]
            const int bb = stid >> 5;
            const int i = (stid & 31) * 4;
            *(float4*)(inu_sh + bb * DINV + i) =
                *(const float4*)(inu + ((size_t)bb * NINV + n_p) * DINV + i);
        }
        __syncthreads();

        {   // GEMM1: thread (bg,e) handles b=2bg,2bg+1
            const int bg = stid >> 6;
            const int e = stid & 63;
            const float* rwp = rw + (size_t)no * DINV * EE + e;
            const float* r0 = inu_sh + (bg * 2) * DINV;
            const float* r1 = inu_sh + (bg * 2 + 1) * DINV;
            float a0 = 0.0f, a1 = 0.0f;
            for (int d = 0; d < DINV; ++d) {
                const float w = rwp[d * EE];
                a0 = fmaf(r0[d], w, a0);
                a1 = fmaf(r1[d], w, a1);
            }
            pri_sh[(bg * 2) * 68 + e] = a0;
            pri_sh[(bg * 2 + 1) * 68 + e] = a1;
        }
        __syncthreads();

        {   // GEMM2: thread (bq, e-pair) -> u16 global
            const int bq = stid >> 5;
            const int e0 = (stid & 31) * 2;
            float b0 = bu[e0], b1 = bu[e0 + 1];
            const float* p = pri_sh + bq * 68;
            for (int e1 = 0; e1 < EE; ++e1) {
                const float2 w = *(const float2*)&Wu[e1 * EE + e0];
                b0 = fmaf(p[e1], w.x, b0);
                b1 = fmaf(p[e1], w.y, b1);
            }
            pk16 pk;
            pk.h = __builtin_amdgcn_cvt_pkrtz(b0 * SA_F, b1 * SA_F);
            *(unsigned int*)((char*)u16 + (((size_t)bq * 1024 + no) * EE + e0) * 2) = pk.u;
        }
        __syncthreads();

        // ---- prep-c for this bl (tid<256); actn (blocks 0..7, tid 256..319)
        if (tid < 256) {
            ph1[tid] = ctx[(size_t)bl * DCV + tid];
            ph1[tid + 256] = ctx[(size_t)bl * DCV + tid + 256];
        } else if (tid < 256 + NINV && bl < BB) {
            const int nn = tid - 256;
            const float* ir = inu + ((size_t)bl * NINV + nn) * DINV;
            float acc = ba[0];
            for (int d = 0; d < DINV; ++d) acc = fmaf(ir[d], Wa[d], acc);
            a_ws[bl * NINV + nn] = 1.0f / (1.0f + expf(-acc));
        }
        __syncthreads();
        if (tid < 256) {   // c GEMM, 4-way d-split
            const int q = tid >> 6;
            const int e = tid & 63;
            const float* rp = ph1 + q * 128;
            const float* wp = Wc + (q * 128) * EE + e;
            float acc = 0.0f;
            for (int d = 0; d < 128; ++d) acc = fmaf(rp[d], wp[d * EE], acc);
            ph1[512 + q * 64 + e] = acc;
        }
        __syncthreads();
        if (tid < EE) {
            const float c = ph1[512 + tid] + ph1[576 + tid] + ph1[640 + tid]
                          + ph1[704 + tid] + bc[tid];
            ph1[768 + tid] = tanhf(c);
        }
        __syncthreads();
        if (tid < EE) {    // vbar (exact f32) + scwv -> swizzled LDS
            const int t = tid;
            float vb = bv[t];
            pk16 scw[32];
            #pragma unroll
            for (int e2 = 0; e2 < 32; ++e2) {
                const float t0 = ph1[768 + 2 * e2], t1 = ph1[768 + 2 * e2 + 1];
                const float w0 = Wv[(2 * e2) * EE + t];
                const float w1 = Wv[(2 * e2 + 1) * EE + t];
                vb = fmaf(t0, w0, fmaf(t1, w1, vb));
                const float s0 = fmaf(-t0, t0, 1.0f) * w0 * SB_F;
                const float s1 = fmaf(-t1, t1, 1.0f) * w1 * SB_F;
                scw[e2].h = __builtin_amdgcn_cvt_pkrtz(s0, s1);
            }
            vbar_sh[t] = vb;
            #pragma unroll
            for (int q = 0; q < 8; ++q) {    // chunk q -> swizzled slot q^(t&7)
                uint4 v;
                v.x = scw[q * 4 + 0].u;
                v.y = scw[q * 4 + 1].u;
                v.z = scw[q * 4 + 2].u;
                v.w = scw[q * 4 + 3].u;
                *(uint4*)((char*)scwv_sh + t * 128 + ((q ^ (t & 7)) << 4)) = v;
            }
        }
    }

    cg::this_grid().sync();              // u16 + actn cross-block deps

    // ================= Phase 2 =================
    if (tid < NINV) actn_sh[tid] = a_ws[b * NINV + tid];

    // ---- A-fragments (scwv, from swizzled LDS): row=e_out=ct*16+l15 ----
    f16x8 bfr[4][2];
    #pragma unroll
    for (int ct = 0; ct < 4; ++ct) {
        const int row = ct * 16 + l15;
        #pragma unroll
        for (int kh = 0; kh < 2; ++kh) {
            const int kc = kh * 4 + (lane >> 4);
            bfr[ct][kh] = *(const f16x8*)((const char*)scwv_sh +
                row * 128 + ((kc ^ (row & 7)) << 4));
        }
    }

    // ---- Phase A: dv = u @ scwv via mfma(scwv, u) -> b64 swizzled stores ----
    {
        const char* urow = (const char*)u16 +
            ((size_t)b * 1024 + wid * 64 + l15) * EE * 2;
        #pragma unroll
        for (int rt = 0; rt < 4; ++rt) {
            const char* up = urow + (size_t)rt * 16 * EE * 2;
            const f16x8 a0 = *(const f16x8*)(up + lk * 2);
            const f16x8 a1 = *(const f16x8*)(up + 64 + lk * 2);
            const int row = wid * 64 + rt * 16 + l15;      // dv row (= B's n)
            const int rsw = (row & 7);
            #pragma unroll
            for (int ct = 0; ct < 4; ++ct) {
                f32x4v acc = {0.0f, 0.0f, 0.0f, 0.0f};
                acc = __builtin_amdgcn_mfma_f32_16x16x32_f16(bfr[ct][0], a0, acc, 0, 0, 0);
                acc = __builtin_amdgcn_mfma_f32_16x16x32_f16(bfr[ct][1], a1, acc, 0, 0, 0);
                const int e0c = ct * 16 + (lane >> 4) * 4; // 4 consecutive e's
                const int kc = e0c >> 3;
                uint2 pk2;
                pk2.x = cvt_pk_bf16(acc[0] * DESCALE, acc[1] * DESCALE);
                pk2.y = cvt_pk_bf16(acc[2] * DESCALE, acc[3] * DESCALE);
                *(uint2*)(dvb + row * 128 + ((kc ^ rsw) << 4) + ((e0c & 7) << 1)) = pk2;
            }
        }
    }
    __syncthreads();                                   // dv + actn staging ready

    const unsigned char msk = mask_all[b * NINV + n];
    float r_loc = 1.0f / 16.0f;

    // m-pass lane roles (one o per wave)
    const int o_m = wid;
    const int eq = lane & 15;
    const int qn = lane >> 4;
    const int e0m = eq * 4;
    const char* dvp = dvb + qn * 32768 + o_m * 128
                    + (((eq >> 1) ^ (o_m & 7)) << 4) + ((eq & 1) << 3);
    const float4* ar4 = (const float4*)&ar_t[o_m][qn * 16];

    for (int it = 0; it < 3; ++it) {
        float arv = actn_sh[n] * r_loc;
        float s = arv;
        s += __shfl_xor(s, 1, 64);
        s += __shfl_xor(s, 2, 64);
        s += __shfl_xor(s, 4, 64);
        s += __shfl_xor(s, 8, 64);
        arv = arv / (s + EPSF);
        ar_t[o][n] = arv;
        __syncthreads();                               // B1

        if (it < 2) {
            float S10 = 0.0f, S11 = 0.0f, S12 = 0.0f, S13 = 0.0f;
            float S20 = 0.0f, S21 = 0.0f, S22 = 0.0f, S23 = 0.0f;
            float A = 0.0f;
            #pragma unroll
            for (int g = 0; g < 4; ++g) {
                const float4 ag = ar4[g];
                #pragma unroll
                for (int i2 = 0; i2 < 4; ++i2) {
                    const float av = (i2 == 0) ? ag.x : (i2 == 1) ? ag.y
                                   : (i2 == 2) ? ag.z : ag.w;
                    const uint2 w2 = *(const uint2*)(dvp + (g * 4 + i2) * 2048);
                    const float v0 = __uint_as_float(w2.x << 16);
                    const float v1 = __uint_as_float(w2.x & 0xFFFF0000u);
                    const float v2 = __uint_as_float(w2.y << 16);
                    const float v3 = __uint_as_float(w2.y & 0xFFFF0000u);
                    A += av;
                    S10 = fmaf(av, v0, S10);  S20 = fmaf(av * v0, v0, S20);
                    S11 = fmaf(av, v1, S11);  S21 = fmaf(av * v1, v1, S21);
                    S12 = fmaf(av, v2, S12);  S22 = fmaf(av * v2, v2, S22);
                    S13 = fmaf(av, v3, S13);  S23 = fmaf(av * v3, v3, S23);
                }
            }
            S10 += __shfl_xor(S10, 16, 64); S10 += __shfl_xor(S10, 32, 64);
            S11 += __shfl_xor(S11, 16, 64); S11 += __shfl_xor(S11, 32, 64);
            S12 += __shfl_xor(S12, 16, 64); S12 += __shfl_xor(S12, 32, 64);
            S13 += __shfl_xor(S13, 16, 64); S13 += __shfl_xor(S13, 32, 64);
            S20 += __shfl_xor(S20, 16, 64); S20 += __shfl_xor(S20, 32, 64);
            S21 += __shfl_xor(S21, 16, 64); S21 += __shfl_xor(S21, 32, 64);
            S22 += __shfl_xor(S22, 16, 64); S22 += __shfl_xor(S22, 32, 64);
            S23 += __shfl_xor(S23, 16, 64); S23 += __shfl_xor(S23, 32, 64);
            A   += __shfl_xor(A, 16, 64);   A   += __shfl_xor(A, 32, 64);

            const float iD = 1.0f / (A + EPSF);
            const float m0 = S10 * iD, m1 = S11 * iD, m2 = S12 * iD, m3 = S13 * iD;
            const float sa0 = fmaxf(fmaf(-m0, m0, S20 * iD), 0.0f) + EPSF;
            const float sa1 = fmaxf(fmaf(-m1, m1, S21 * iD), 0.0f) + EPSF;
            const float sa2 = fmaxf(fmaf(-m2, m2, S22 * iD), 0.0f) + EPSF;
            const float sa3 = fmaxf(fmaf(-m3, m3, S23 * iD), 0.0f) + EPSF;
            if (qn == 0) {
                *(float4*)&dmu_sh[o_m][e0m] = make_float4(m0, m1, m2, m3);
                *(float4*)&q_sh[o_m][e0m] =
                    make_float4(0.5f / sa0, 0.5f / sa1, 0.5f / sa2, 0.5f / sa3);
            }
            float hl = 0.5f * (logf(sa0) + logf(sa1) + logf(sa2) + logf(sa3));
            hl += __shfl_xor(hl, 1, 64);
            hl += __shfl_xor(hl, 2, 64);
            hl += __shfl_xor(hl, 4, 64);
            hl += __shfl_xor(hl, 8, 64);
            if (lane == 0) {
                sumhl_sh[o_m] = hl;
                const float cost = 64.0f * beta_u[o_m] + A * hl;
                const float x = LBDF * (beta_a[o_m] - cost);
                logact_sh[o_m] = logf(1.0f / (1.0f + expf(-x)));
            }
            __syncthreads();                           // B2

            // ---- e-step: all 1024, role (n,o) ----
            const float4* dmu4 = (const float4*)&dmu_sh[o][0];
            const float4* qq4 = (const float4*)&q_sh[o][0];
            const int row = (n << 4) | o;
            const int swz8 = o & 7;
            float acc2 = 0.0f;
            #pragma unroll
            for (int kc = 0; kc < 8; ++kc) {
                const uint4 w = *(const uint4*)(dvb + row * 128 + ((kc ^ swz8) * 16));
                const float4 mm0 = dmu4[kc * 2], mm1 = dmu4[kc * 2 + 1];
                const float4 q0 = qq4[kc * 2], q1 = qq4[kc * 2 + 1];
                float d;
                d = __uint_as_float(w.x << 16) - mm0.x;         acc2 = fmaf(d * d, q0.x, acc2);
                d = __uint_as_float(w.x & 0xFFFF0000u) - mm0.y; acc2 = fmaf(d * d, q0.y, acc2);
                d = __uint_as_float(w.y << 16) - mm0.z;         acc2 = fmaf(d * d, q0.z, acc2);
                d = __uint_as_float(w.y & 0xFFFF0000u) - mm0.w; acc2 = fmaf(d * d, q0.w, acc2);
                d = __uint_as_float(w.z << 16) - mm1.x;         acc2 = fmaf(d * d, q1.x, acc2);
                d = __uint_as_float(w.z & 0xFFFF0000u) - mm1.y; acc2 = fmaf(d * d, q1.y, acc2);
                d = __uint_as_float(w.w << 16) - mm1.z;         acc2 = fmaf(d * d, q1.z, acc2);
                d = __uint_as_float(w.w & 0xFFFF0000u) - mm1.w; acc2 = fmaf(d * d, q1.w, acc2);
            }
            float la = -acc2 - sumhl_sh[o] - SUM_LN2PI + logact_sh[o];
            if (msk) la = -10000.0f;
            float mx = la;
            mx = fmaxf(mx, __shfl_xor(mx, 1, 64));
            mx = fmaxf(mx, __shfl_xor(mx, 2, 64));
            mx = fmaxf(mx, __shfl_xor(mx, 4, 64));
            mx = fmaxf(mx, __shfl_xor(mx, 8, 64));
            const float ex = __expf(la - mx);
            float se = ex;
            se += __shfl_xor(se, 1, 64);
            se += __shfl_xor(se, 2, 64);
            se += __shfl_xor(se, 4, 64);
            se += __shfl_xor(se, 8, 64);
            r_loc = ex / se;
        } else {
            // ---- final m-step: mu only ----
            float S10 = 0.0f, S11 = 0.0f, S12 = 0.0f, S13 = 0.0f;
            float A = 0.0f;
            #pragma unroll
            for (int g = 0; g < 4; ++g) {
                const float4 ag = ar4[g];
                #pragma unroll
                for (int i2 = 0; i2 < 4; ++i2) {
                    const float av = (i2 == 0) ? ag.x : (i2 == 1) ? ag.y
                                   : (i2 == 2) ? ag.z : ag.w;
                    const uint2 w2 = *(const uint2*)(dvp + (g * 4 + i2) * 2048);
                    A += av;
                    S10 = fmaf(av, __uint_as_float(w2.x << 16), S10);
                    S11 = fmaf(av, __uint_as_float(w2.x & 0xFFFF0000u), S11);
                    S12 = fmaf(av, __uint_as_float(w2.y << 16), S12);
                    S13 = fmaf(av, __uint_as_float(w2.y & 0xFFFF0000u), S13);
                }
            }
            S10 += __shfl_xor(S10, 16, 64); S10 += __shfl_xor(S10, 32, 64);
            S11 += __shfl_xor(S11, 16, 64); S11 += __shfl_xor(S11, 32, 64);
            S12 += __shfl_xor(S12, 16, 64); S12 += __shfl_xor(S12, 32, 64);
            S13 += __shfl_xor(S13, 16, 64); S13 += __shfl_xor(S13, 32, 64);
            A   += __shfl_xor(A, 16, 64);   A   += __shfl_xor(A, 32, 64);
            const float iD = 1.0f / (A + EPSF);
            if (qn == 0) {
                const float4 outv = make_float4(
                    vbar_sh[e0m + 0] + S10 * iD,
                    vbar_sh[e0m + 1] + S11 * iD,
                    vbar_sh[e0m + 2] + S12 * iD,
                    vbar_sh[e0m + 3] + S13 * iD);
                *(float4*)&out_mu[bl * 1024 + o_m * EE + e0m] = outv;
            }
        }
    }

    out_r[bl * 1024 + tid] = r_loc;    // tid == n*16+o
}

// ---------------------------------------------------------------------------
extern "C" void kernel_launch(void* const* d_in, const int* in_sizes, int n_in,
                              void* d_out, int out_size, void* d_ws, size_t ws_size,
                              hipStream_t stream) {
    const float* inu            = (const float*)d_in[0];
    const unsigned char* mask   = (const unsigned char*)d_in[1];
    const float* ctx            = (const float*)d_in[2];
    const float* rw             = (const float*)d_in[3];
    const float* Wu             = (const float*)d_in[4];
    const float* bu             = (const float*)d_in[5];
    const float* Wc             = (const float*)d_in[6];
    const float* bc             = (const float*)d_in[7];
    const float* Wv             = (const float*)d_in[8];
    const float* bv             = (const float*)d_in[9];
    const float* Wa             = (const float*)d_in[10];
    const float* ba             = (const float*)d_in[11];
    const float* beta_u         = (const float*)d_in[12];
    const float* beta_a         = (const float*)d_in[13];

    _Float16* u16 = (_Float16*)d_ws;                          // 1 MB
    float* a_ws   = (float*)(u16 + (size_t)BB * 1024 * EE);   // 2 KB

    float* out_mu = (float*)d_out;
    float* out_r  = out_mu + (size_t)BB * LL * NOUTV * EE;

    void* args[] = {
        (void*)&inu, (void*)&rw, (void*)&Wu, (void*)&bu,
        (void*)&ctx, (void*)&Wc, (void*)&bc, (void*)&Wv, (void*)&bv,
        (void*)&Wa, (void*)&ba, (void*)&mask, (void*)&beta_u, (void*)&beta_a,
        (void*)&u16, (void*)&a_ws, (void*)&out_mu, (void*)&out_r
    };
    hipLaunchCooperativeKernel((void*)fused_all_kernel, dim3(BB * LL), dim3(1024),
                               args, 0, stream);
}

// Round 18
// 43.527 us; speedup vs baseline: 1.7295x; 1.7295x over previous
//
#include <hip/hip_runtime.h>
#include <hip/hip_bf16.h>

// Problem dims (fixed)
#define BB   8
#define LL   32
#define NINV 64
#define NOUTV 16
#define DINV 128
#define EE   64
#define DCV  512

#define EPSF 1e-8f
#define LBDF 1e-3f
// 32 * ln(2*pi)
#define SUM_LN2PI 58.8120661250990508f

// f16 MFMA scaling: A(u) x 2^12, B(sc*Wv) x 2^10, descale 2^-22
#define SA_F 4096.0f
#define SB_F 1024.0f
#define DESCALE (1.0f / 4194304.0f)

typedef float f32x4v __attribute__((ext_vector_type(4)));
typedef _Float16 f16x8 __attribute__((ext_vector_type(8)));
typedef __fp16 fp16x2 __attribute__((ext_vector_type(2)));

union pk16 { fp16x2 h; unsigned int u; };

static __device__ __forceinline__ unsigned int cvt_pk_bf16(float lo, float hi) {
    unsigned int r;
    asm("v_cvt_pk_bf16_f32 %0, %1, %2" : "=v"(r) : "v"(lo), "v"(hi));
    return r;
}

// ---------------------------------------------------------------------------
// Kernel 1 (merged front-end, R14/R16 form), 1288 blocks x 256 threads:
//  blk < 1024: priors = inu@rw (VALU, coalesced); u = priors@Wu+bu -> f16x2^12
//  1024..1279: c = ctx@Wc+bc; tc=tanh(c); vbar = tc@Wv+bv (exact f32);
//              scWv[bl][e_out][k] = sech2(c)[k]*Wv[k][e_out] f16 x 2^10
//  1280..1287: actn = sigmoid(inu@Wa+ba)
// R17 lesson: this kernel MUST keep its own high-occupancy launch (~32
// waves/CU); folding it into the 1-block/CU em kernel cost ~25us.
// ---------------------------------------------------------------------------
__global__ __launch_bounds__(256) void pre_kernel(
    const float* __restrict__ inu, const float* __restrict__ rw,
    const float* __restrict__ Wu, const float* __restrict__ bu,
    const float* __restrict__ ctx, const float* __restrict__ Wc, const float* __restrict__ bc,
    const float* __restrict__ Wv, const float* __restrict__ bv,
    const float* __restrict__ Wa, const float* __restrict__ ba,
    _Float16* __restrict__ u16, _Float16* __restrict__ scwv,
    float* __restrict__ vbar_out, float* __restrict__ actn_out)
{
    const int blk = blockIdx.x;
    const int tid = threadIdx.x;
    __shared__ float sh_a[BB * DINV];     // priors: inu_sh | prep: ctx row(512)+part(256)
    __shared__ float sh_b[BB * EE];       // priors: pri_sh | prep: tc_sh

    if (blk < NINV * NOUTV) {
        // ---------------- priors + u (f16) ----------------
        const int n  = blk >> 4;
        {   // stage inu[:, n, :]
            const int b = tid >> 5;
            const int i = (tid & 31) * 4;
            const float4 s = *(const float4*)(inu + ((size_t)b * NINV + n) * DINV + i);
            *(float4*)(sh_a + b * DINV + i) = s;
        }
        __syncthreads();

        {   // GEMM1: thread (bg,e) handles b=2bg,2bg+1
            const int bg = tid >> 6;
            const int e  = tid & 63;
            const float* rwp = rw + (size_t)blk * DINV * EE + e;
            const float* r0 = sh_a + (bg * 2) * DINV;
            const float* r1 = sh_a + (bg * 2 + 1) * DINV;
            float a0 = 0.0f, a1 = 0.0f;
            for (int d = 0; d < DINV; ++d) {
                const float w = rwp[d * EE];
                a0 = fmaf(r0[d], w, a0);
                a1 = fmaf(r1[d], w, a1);
            }
            sh_b[(bg * 2) * EE + e] = a0;
            sh_b[(bg * 2 + 1) * EE + e] = a1;
        }
        __syncthreads();

        // GEMM2: thread (bq, e-pair); u -> f16 x 2^12, coalesced dwords
        const int bq = tid >> 5;
        const int e0 = (tid & 31) * 2;
        float b0 = bu[e0], b1 = bu[e0 + 1];
        const float* p = sh_b + bq * EE;
        for (int e1 = 0; e1 < EE; ++e1) {
            const float2 w = *(const float2*)&Wu[e1 * EE + e0];
            b0 = fmaf(p[e1], w.x, b0);
            b1 = fmaf(p[e1], w.y, b1);
        }
        pk16 pk;
        pk.h = __builtin_amdgcn_cvt_pkrtz(b0 * SA_F, b1 * SA_F);
        *(unsigned int*)((char*)u16 + (((size_t)bq * 1024 + blk) * EE + e0) * 2) = pk.u;

    } else if (blk < NINV * NOUTV + BB * LL) {
        // ---------------- prep-c: c, vbar, scWv ----------------
        const int bl = blk - NINV * NOUTV;
        const float* cr = ctx + (size_t)bl * DCV;
        sh_a[tid] = cr[tid];
        sh_a[tid + 256] = cr[tid + 256];
        __syncthreads();
        {
            const int q = tid >> 6;
            const int e = tid & 63;
            const float* rp = sh_a + q * 128;
            const float* wp = Wc + (q * 128) * EE + e;
            float acc = 0.0f;
            for (int d = 0; d < 128; ++d) acc = fmaf(rp[d], wp[d * EE], acc);
            sh_a[512 + q * 64 + e] = acc;
        }
        __syncthreads();
        if (tid < EE) {
            const float c = sh_a[512 + tid] + sh_a[576 + tid] + sh_a[640 + tid]
                          + sh_a[704 + tid] + bc[tid];
            sh_b[tid] = tanhf(c);
        }
        __syncthreads();
        if (tid < EE) {
            const int t = tid;
            float vb = bv[t];
            pk16 scw[32];
            #pragma unroll
            for (int e2 = 0; e2 < 32; ++e2) {
                const float t0 = sh_b[2 * e2], t1 = sh_b[2 * e2 + 1];
                const float w0 = Wv[(2 * e2) * EE + t];
                const float w1 = Wv[(2 * e2 + 1) * EE + t];
                vb = fmaf(t0, w0, fmaf(t1, w1, vb));
                const float s0 = fmaf(-t0, t0, 1.0f) * w0 * SB_F;
                const float s1 = fmaf(-t1, t1, 1.0f) * w1 * SB_F;
                scw[e2].h = __builtin_amdgcn_cvt_pkrtz(s0, s1);
            }
            vbar_out[bl * EE + t] = vb;
            uint4* dst = (uint4*)((char*)scwv + ((size_t)bl * EE + t) * EE * 2);
            #pragma unroll
            for (int q = 0; q < 8; ++q) {
                uint4 v;
                v.x = scw[q * 4 + 0].u;
                v.y = scw[q * 4 + 1].u;
                v.z = scw[q * 4 + 2].u;
                v.w = scw[q * 4 + 3].u;
                dst[q] = v;
            }
        }
    } else {
        // ---------------- actn ----------------
        const int b = blk - (NINV * NOUTV + BB * LL);
        if (tid < NINV) {
            const float* ir = inu + ((size_t)b * NINV + tid) * DINV;
            float acc = ba[0];
            for (int d = 0; d < DINV; ++d) acc = fmaf(ir[d], Wa[d], acc);
            actn_out[b * NINV + tid] = 1.0f / (1.0f + expf(-acc));
        }
    }
}

// ---------------------------------------------------------------------------
// Kernel 2 (fused): one 1024-thread block per (b,l).
// Phase A (R17-VERIFIED swap): dv = u @ scwv via mfma(scwv_frag, u_frag) --
// A/B fragment lane layouts are symmetric so loads are unchanged, but D's
// reg index now walks e_out -> ONE ds_write_b64 per (rt,ct) instead of
// 4 scalar b16 scatters (64 -> 16 LDS write ops/lane).
// Phase B: EM in the R16 wave-per-o m-pass form (proven).
// ---------------------------------------------------------------------------
__global__ __launch_bounds__(1024) void em_fused_kernel(
    const _Float16* __restrict__ u16, const _Float16* __restrict__ scwv,
    const float* __restrict__ vbar_all, const float* __restrict__ actn_all,
    const unsigned char* __restrict__ mask_all,
    const float* __restrict__ beta_u, const float* __restrict__ beta_a,
    float* __restrict__ out_mu, float* __restrict__ out_r)
{
    const int bl = blockIdx.x;           // 0..255  (= b*32 + l)
    const int b = bl >> 5;
    const int tid = threadIdx.x;
    const int n = tid >> 4;              // e-step role
    const int o = tid & 15;
    const int wid = tid >> 6;            // wave 0..15
    const int lane = tid & 63;
    const int l15 = lane & 15;
    const int lk = (lane >> 4) * 8;      // k-offset of this lane's A/B elems

    __shared__ __align__(16) unsigned int dv_sh[NINV * NOUTV * (EE / 2)]; // 128 KB
    __shared__ __align__(16) float dmu_sh[NOUTV][68];
    __shared__ __align__(16) float q_sh[NOUTV][68];
    __shared__ __align__(16) float ar_t[NOUTV][68];     // transposed: [o][n]
    __shared__ float actn_sh[NINV];
    __shared__ float vbar_sh[EE];
    __shared__ float sumhl_sh[NOUTV];
    __shared__ float logact_sh[NOUTV];

    char* dvb = (char*)dv_sh;

    if (tid < NINV) actn_sh[tid] = actn_all[b * NINV + tid];
    else if (tid < NINV + EE) vbar_sh[tid - NINV] = vbar_all[bl * EE + (tid - NINV)];

    // ---- scwv fragments (A-operand after swap): row = e_out = ct*16+l15 ----
    f16x8 bfr[4][2];
    #pragma unroll
    for (int ct = 0; ct < 4; ++ct) {
        #pragma unroll
        for (int kh = 0; kh < 2; ++kh) {
            bfr[ct][kh] = *(const f16x8*)((const char*)scwv +
                (((size_t)bl * EE + (ct * 16 + l15)) * EE + kh * 32 + lk) * 2);
        }
    }

    // ---- Phase A: dv via mfma(scwv, u) -> b64 swizzled stores ----
    {
        const char* urow = (const char*)u16 +
            ((size_t)b * 1024 + wid * 64 + l15) * EE * 2;
        #pragma unroll
        for (int rt = 0; rt < 4; ++rt) {
            const char* up = urow + (size_t)rt * 16 * EE * 2;
            const f16x8 a0 = *(const f16x8*)(up + lk * 2);
            const f16x8 a1 = *(const f16x8*)(up + 64 + lk * 2);
            const int row = wid * 64 + rt * 16 + l15;      // dv row (u-row)
            const int rsw = (row & 7);
            #pragma unroll
            for (int ct = 0; ct < 4; ++ct) {
                f32x4v acc = {0.0f, 0.0f, 0.0f, 0.0f};
                acc = __builtin_amdgcn_mfma_f32_16x16x32_f16(bfr[ct][0], a0, acc, 0, 0, 0);
                acc = __builtin_amdgcn_mfma_f32_16x16x32_f16(bfr[ct][1], a1, acc, 0, 0, 0);
                const int e0c = ct * 16 + (lane >> 4) * 4; // 4 consecutive e's
                const int kc = e0c >> 3;
                uint2 pk2;
                pk2.x = cvt_pk_bf16(acc[0] * DESCALE, acc[1] * DESCALE);
                pk2.y = cvt_pk_bf16(acc[2] * DESCALE, acc[3] * DESCALE);
                *(uint2*)(dvb + row * 128 + ((kc ^ rsw) << 4) + ((e0c & 7) << 1)) = pk2;
            }
        }
    }
    __syncthreads();                                   // dv + staging ready

    const unsigned char msk = mask_all[b * NINV + n];
    float r_loc = 1.0f / 16.0f;

    // m-pass lane roles (one o per wave)
    const int o_m = wid;
    const int eq = lane & 15;            // e-quad: e0 = eq*4
    const int qn = lane >> 4;            // n-quarter
    const int e0m = eq * 4;
    const char* dvp = dvb + qn * 32768 + o_m * 128
                    + (((eq >> 1) ^ (o_m & 7)) << 4) + ((eq & 1) << 3);
    const float4* ar4 = (const float4*)&ar_t[o_m][qn * 16];

    for (int it = 0; it < 3; ++it) {
        // ---- ar (normalized over o), write transposed to LDS ----
        float arv = actn_sh[n] * r_loc;
        float s = arv;
        s += __shfl_xor(s, 1, 64);
        s += __shfl_xor(s, 2, 64);
        s += __shfl_xor(s, 4, 64);
        s += __shfl_xor(s, 8, 64);
        arv = arv / (s + EPSF);
        ar_t[o][n] = arv;
        __syncthreads();                               // B1

        if (it < 2) {
            // ---- m-pass: all 16 waves; wave o_m; lane (qn, eq) ----
            float S10 = 0.0f, S11 = 0.0f, S12 = 0.0f, S13 = 0.0f;
            float S20 = 0.0f, S21 = 0.0f, S22 = 0.0f, S23 = 0.0f;
            float A = 0.0f;
            #pragma unroll
            for (int g = 0; g < 4; ++g) {
                const float4 ag = ar4[g];
                #pragma unroll
                for (int i2 = 0; i2 < 4; ++i2) {
                    const float av = (i2 == 0) ? ag.x : (i2 == 1) ? ag.y
                                   : (i2 == 2) ? ag.z : ag.w;
                    const uint2 w2 = *(const uint2*)(dvp + (g * 4 + i2) * 2048);
                    const float v0 = __uint_as_float(w2.x << 16);
                    const float v1 = __uint_as_float(w2.x & 0xFFFF0000u);
                    const float v2 = __uint_as_float(w2.y << 16);
                    const float v3 = __uint_as_float(w2.y & 0xFFFF0000u);
                    A += av;
                    S10 = fmaf(av, v0, S10);  S20 = fmaf(av * v0, v0, S20);
                    S11 = fmaf(av, v1, S11);  S21 = fmaf(av * v1, v1, S21);
                    S12 = fmaf(av, v2, S12);  S22 = fmaf(av * v2, v2, S22);
                    S13 = fmaf(av, v3, S13);  S23 = fmaf(av * v3, v3, S23);
                }
            }
            S10 += __shfl_xor(S10, 16, 64); S10 += __shfl_xor(S10, 32, 64);
            S11 += __shfl_xor(S11, 16, 64); S11 += __shfl_xor(S11, 32, 64);
            S12 += __shfl_xor(S12, 16, 64); S12 += __shfl_xor(S12, 32, 64);
            S13 += __shfl_xor(S13, 16, 64); S13 += __shfl_xor(S13, 32, 64);
            S20 += __shfl_xor(S20, 16, 64); S20 += __shfl_xor(S20, 32, 64);
            S21 += __shfl_xor(S21, 16, 64); S21 += __shfl_xor(S21, 32, 64);
            S22 += __shfl_xor(S22, 16, 64); S22 += __shfl_xor(S22, 32, 64);
            S23 += __shfl_xor(S23, 16, 64); S23 += __shfl_xor(S23, 32, 64);
            A   += __shfl_xor(A, 16, 64);   A   += __shfl_xor(A, 32, 64);

            const float iD = 1.0f / (A + EPSF);
            const float m0 = S10 * iD, m1 = S11 * iD, m2 = S12 * iD, m3 = S13 * iD;
            const float sa0 = fmaxf(fmaf(-m0, m0, S20 * iD), 0.0f) + EPSF;
            const float sa1 = fmaxf(fmaf(-m1, m1, S21 * iD), 0.0f) + EPSF;
            const float sa2 = fmaxf(fmaf(-m2, m2, S22 * iD), 0.0f) + EPSF;
            const float sa3 = fmaxf(fmaf(-m3, m3, S23 * iD), 0.0f) + EPSF;
            if (qn == 0) {
                *(float4*)&dmu_sh[o_m][e0m] = make_float4(m0, m1, m2, m3);
                *(float4*)&q_sh[o_m][e0m] =
                    make_float4(0.5f / sa0, 0.5f / sa1, 0.5f / sa2, 0.5f / sa3);
            }
            float hl = 0.5f * (logf(sa0) + logf(sa1) + logf(sa2) + logf(sa3));
            hl += __shfl_xor(hl, 1, 64);
            hl += __shfl_xor(hl, 2, 64);
            hl += __shfl_xor(hl, 4, 64);
            hl += __shfl_xor(hl, 8, 64);
            if (lane == 0) {
                sumhl_sh[o_m] = hl;
                const float cost = 64.0f * beta_u[o_m] + A * hl;
                const float x = LBDF * (beta_a[o_m] - cost);
                logact_sh[o_m] = logf(1.0f / (1.0f + expf(-x)));
            }
            __syncthreads();                           // B2

            // ---- e-step: all 1024, role (n,o) ----
            const float4* dmu4 = (const float4*)&dmu_sh[o][0];
            const float4* qq4 = (const float4*)&q_sh[o][0];
            const int row = (n << 4) | o;
            const int swz8 = o & 7;
            float acc2 = 0.0f;
            #pragma unroll
            for (int kc = 0; kc < 8; ++kc) {
                const uint4 w = *(const uint4*)(dvb + row * 128 + ((kc ^ swz8) * 16));
                const float4 mm0 = dmu4[kc * 2], mm1 = dmu4[kc * 2 + 1];
                const float4 q0 = qq4[kc * 2], q1 = qq4[kc * 2 + 1];
                float d;
                d = __uint_as_float(w.x << 16) - mm0.x;         acc2 = fmaf(d * d, q0.x, acc2);
                d = __uint_as_float(w.x & 0xFFFF0000u) - mm0.y; acc2 = fmaf(d * d, q0.y, acc2);
                d = __uint_as_float(w.y << 16) - mm0.z;         acc2 = fmaf(d * d, q0.z, acc2);
                d = __uint_as_float(w.y & 0xFFFF0000u) - mm0.w; acc2 = fmaf(d * d, q0.w, acc2);
                d = __uint_as_float(w.z << 16) - mm1.x;         acc2 = fmaf(d * d, q1.x, acc2);
                d = __uint_as_float(w.z & 0xFFFF0000u) - mm1.y; acc2 = fmaf(d * d, q1.y, acc2);
                d = __uint_as_float(w.w << 16) - mm1.z;         acc2 = fmaf(d * d, q1.z, acc2);
                d = __uint_as_float(w.w & 0xFFFF0000u) - mm1.w; acc2 = fmaf(d * d, q1.w, acc2);
            }
            float la = -acc2 - sumhl_sh[o] - SUM_LN2PI + logact_sh[o];
            if (msk) la = -10000.0f;
            float mx = la;
            mx = fmaxf(mx, __shfl_xor(mx, 1, 64));
            mx = fmaxf(mx, __shfl_xor(mx, 2, 64));
            mx = fmaxf(mx, __shfl_xor(mx, 4, 64));
            mx = fmaxf(mx, __shfl_xor(mx, 8, 64));
            const float ex = __expf(la - mx);
            float se = ex;
            se += __shfl_xor(se, 1, 64);
            se += __shfl_xor(se, 2, 64);
            se += __shfl_xor(se, 4, 64);
            se += __shfl_xor(se, 8, 64);
            r_loc = ex / se;
        } else {
            // ---- final m-step: mu only (same wave layout) ----
            float S10 = 0.0f, S11 = 0.0f, S12 = 0.0f, S13 = 0.0f;
            float A = 0.0f;
            #pragma unroll
            for (int g = 0; g < 4; ++g) {
                const float4 ag = ar4[g];
                #pragma unroll
                for (int i2 = 0; i2 < 4; ++i2) {
                    const float av = (i2 == 0) ? ag.x : (i2 == 1) ? ag.y
                                   : (i2 == 2) ? ag.z : ag.w;
                    const uint2 w2 = *(const uint2*)(dvp + (g * 4 + i2) * 2048);
                    A += av;
                    S10 = fmaf(av, __uint_as_float(w2.x << 16), S10);
                    S11 = fmaf(av, __uint_as_float(w2.x & 0xFFFF0000u), S11);
                    S12 = fmaf(av, __uint_as_float(w2.y << 16), S12);
                    S13 = fmaf(av, __uint_as_float(w2.y & 0xFFFF0000u), S13);
                }
            }
            S10 += __shfl_xor(S10, 16, 64); S10 += __shfl_xor(S10, 32, 64);
            S11 += __shfl_xor(S11, 16, 64); S11 += __shfl_xor(S11, 32, 64);
            S12 += __shfl_xor(S12, 16, 64); S12 += __shfl_xor(S12, 32, 64);
            S13 += __shfl_xor(S13, 16, 64); S13 += __shfl_xor(S13, 32, 64);
            A   += __shfl_xor(A, 16, 64);   A   += __shfl_xor(A, 32, 64);
            const float iD = 1.0f / (A + EPSF);
            if (qn == 0) {
                const float4 outv = make_float4(
                    vbar_sh[e0m + 0] + S10 * iD,
                    vbar_sh[e0m + 1] + S11 * iD,
                    vbar_sh[e0m + 2] + S12 * iD,
                    vbar_sh[e0m + 3] + S13 * iD);
                *(float4*)&out_mu[bl * 1024 + o_m * EE + e0m] = outv;
            }
        }
    }

    out_r[bl * 1024 + tid] = r_loc;    // tid == n*16+o
}

// ---------------------------------------------------------------------------
extern "C" void kernel_launch(void* const* d_in, const int* in_sizes, int n_in,
                              void* d_out, int out_size, void* d_ws, size_t ws_size,
                              hipStream_t stream) {
    const float* inu            = (const float*)d_in[0];
    const unsigned char* mask   = (const unsigned char*)d_in[1];
    const float* ctx            = (const float*)d_in[2];
    const float* rw             = (const float*)d_in[3];
    const float* Wu             = (const float*)d_in[4];
    const float* bu             = (const float*)d_in[5];
    const float* Wc             = (const float*)d_in[6];
    const float* bc             = (const float*)d_in[7];
    const float* Wv             = (const float*)d_in[8];
    const float* bv             = (const float*)d_in[9];
    const float* Wa             = (const float*)d_in[10];
    const float* ba             = (const float*)d_in[11];
    const float* beta_u         = (const float*)d_in[12];
    const float* beta_a         = (const float*)d_in[13];

    _Float16* scwv = (_Float16*)d_ws;                         // 2 MB
    _Float16* u16  = scwv + (size_t)BB * LL * EE * EE;        // 1 MB
    float* vbar_ws = (float*)(u16 + (size_t)BB * 1024 * EE);  // 64 KB
    float* a_ws    = vbar_ws + (size_t)BB * LL * EE;          // 2 KB

    float* out_mu = (float*)d_out;
    float* out_r  = out_mu + (size_t)BB * LL * NOUTV * EE;

    pre_kernel<<<NINV * NOUTV + BB * LL + BB, 256, 0, stream>>>(
        inu, rw, Wu, bu, ctx, Wc, bc, Wv, bv, Wa, ba,
        u16, scwv, vbar_ws, a_ws);
    em_fused_kernel<<<BB * LL, 1024, 0, stream>>>(u16, scwv, vbar_ws, a_ws, mask,
                                                  beta_u, beta_a, out_mu, out_r);
}